// Round 14
// baseline (439.628 us; speedup 1.0000x reference)
//
#include <hip/hip_runtime.h>
#include <math.h>

#define NN 50000
#define EE 800000
#define INC 128
#define HIDC 64
#define OUTC 64
#define LLAYERS 8
#define TOT (EE + NN)
#define SCAN_B 200   // ceil(NN/256)

// Wave-internal LDS fence (vecs[w]/xs[w] wave-private; no block barrier).
#define WAVE_LDS_FENCE() asm volatile("s_waitcnt lgkmcnt(0)" ::: "memory")

// bf16 <-> f32 (RTN-even pack; values are finite)
__device__ __forceinline__ float bf2f(unsigned short u) {
    return __uint_as_float(((unsigned int)u) << 16);
}
__device__ __forceinline__ unsigned short f2bf(float f) {
    unsigned int u = __float_as_uint(f);
    u += 0x7FFFu + ((u >> 16) & 1u);
    return (unsigned short)(u >> 16);
}

// ---------------------------------------------------------------------------
// Stage 0: detect whether edge_index was delivered as int64 or int32.
__global__ void detect_kernel(const long long* __restrict__ p, int* __restrict__ flag) {
    int stride = gridDim.x * blockDim.x;
    int bad = 0;
    for (int i = blockIdx.x * blockDim.x + threadIdx.x; i < EE; i += stride) {
        long long v = p[i];
        bad |= (v < 0 || v >= NN);
    }
    if (bad) atomicOr(flag, 1);   // flag=1 -> int32 layout
}

__device__ __forceinline__ int load_row(const void* ei, int is64, int e) {
    return is64 ? (int)((const long long*)ei)[e] : ((const int*)ei)[e];
}
__device__ __forceinline__ int load_col(const void* ei, int is64, int e) {
    return is64 ? (int)((const long long*)ei)[EE + e] : ((const int*)ei)[EE + e];
}

// Stage 1: in-degree of col (self-loops included)
__global__ void deg_kernel(const void* __restrict__ ei, const int* __restrict__ flag,
                           int* __restrict__ degi) {
    int i = blockIdx.x * blockDim.x + threadIdx.x;
    if (i >= TOT) return;
    int is64 = (*flag == 0);
    int c = (i < EE) ? load_col(ei, is64, i) : (i - EE);
    atomicAdd(&degi[c], 1);
}

__global__ void dinv_kernel(const int* __restrict__ degi, float* __restrict__ dinv) {
    int i = blockIdx.x * blockDim.x + threadIdx.x;
    if (i < NN) {
        int d = degi[i];
        dinv[i] = d > 0 ? 1.0f / sqrtf((float)d) : 0.0f;
    }
}

// ---------------------------------------------------------------------------
// Stage 2: 3-kernel device-wide exclusive scan
__global__ __launch_bounds__(256) void scan_part(const int* __restrict__ degi,
                                                 int* __restrict__ bsum) {
    __shared__ int s[256];
    int t = threadIdx.x;
    int i = blockIdx.x * 256 + t;
    s[t] = (i < NN) ? degi[i] : 0;
    __syncthreads();
    for (int off = 128; off > 0; off >>= 1) {
        if (t < off) s[t] += s[t + off];
        __syncthreads();
    }
    if (t == 0) bsum[blockIdx.x] = s[0];
}

__global__ __launch_bounds__(256) void scan_bsum(int* __restrict__ bsum) {
    __shared__ int s[256];
    int t = threadIdx.x;
    int v = (t < SCAN_B) ? bsum[t] : 0;
    s[t] = v;
    __syncthreads();
    for (int off = 1; off < 256; off <<= 1) {
        int add = (t >= off) ? s[t - off] : 0;
        __syncthreads();
        s[t] += add;
        __syncthreads();
    }
    if (t < SCAN_B) bsum[t] = s[t] - v;   // exclusive
}

__global__ __launch_bounds__(256) void scan_final(const int* __restrict__ degi,
                                                  const int* __restrict__ bsum,
                                                  int* __restrict__ offsets) {
    __shared__ int s[256];
    int t = threadIdx.x;
    int i = blockIdx.x * 256 + t;
    int v = (i < NN) ? degi[i] : 0;
    s[t] = v;
    __syncthreads();
    for (int off = 1; off < 256; off <<= 1) {
        int add = (t >= off) ? s[t - off] : 0;
        __syncthreads();
        s[t] += add;
        __syncthreads();
    }
    if (i < NN) {
        int off_i = bsum[blockIdx.x] + s[t] - v;   // exclusive prefix of degi[i]
        offsets[i] = off_i;
        if (i == NN - 1) offsets[NN] = off_i + v;
    }
}

// Stage 3: fill CSR adjacency (src, norm) sorted by destination
__global__ void fill_kernel(const void* __restrict__ ei, const int* __restrict__ flag,
                            const float* __restrict__ dinv, int* __restrict__ cursor,
                            int2* __restrict__ adj) {
    int i = blockIdx.x * blockDim.x + threadIdx.x;
    if (i >= TOT) return;
    int is64 = (*flag == 0);
    int r, c;
    if (i < EE) { r = load_row(ei, is64, i); c = load_col(ei, is64, i); }
    else        { r = i - EE; c = r; }
    int pos = atomicAdd(&cursor[c], 1);
    adj[pos] = make_int2(r, __float_as_int(dinv[r] * dinv[c]));
}

// ---------------------------------------------------------------------------
// Stage 4: h(bf16) = relu(x @ w_in^T + b_in); x0(fp32) = same.
// W in SLOT-MAJOR float4 layout WI4[s*64 + j]: at dot slot s, lane j reads
// (s*64+j)*16B -> the wave reads 1024 CONTIGUOUS bytes (m134's proven
// conflict-free b128 pattern). Staging write is stride-1 float4.
__global__ __launch_bounds__(512) void in_gemm(const float* __restrict__ x,
                                               const float* __restrict__ w_in,
                                               const float* __restrict__ b_in,
                                               unsigned short* __restrict__ h,
                                               float* __restrict__ x0) {
    __shared__ float4 WI4[32 * HIDC];   // [slot][row], 32KB
    __shared__ float  xs[8][INC];
    int tid = threadIdx.x;
    const float4* wf4 = reinterpret_cast<const float4*>(w_in);  // w_in[j][k] -> wf4[j*32+s]
    for (int m = 0; m < 4; ++m) {
        int idx = tid + m * 512;               // idx = s*64 + j
        int s = idx >> 6, j = idx & 63;
        WI4[idx] = wf4[j * 32 + s];            // scattered L2 read, once per block
    }
    __syncthreads();
    int w = tid >> 6, lane = tid & 63;
    float bj = b_in[lane];
    for (int n0 = blockIdx.x * 8; n0 < NN; n0 += gridDim.x * 8) {
        int n = n0 + w;
        if (n < NN) {
            xs[w][lane]      = x[(size_t)n * INC + lane];
            xs[w][lane + 64] = x[(size_t)n * INC + 64 + lane];
            WAVE_LDS_FENCE();
            float acc = bj;
            #pragma unroll
            for (int s = 0; s < 32; ++s) {
                float4 wv = WI4[(s << 6) + lane];
                float4 xv = *reinterpret_cast<const float4*>(&xs[w][s << 2]);
                acc = fmaf(wv.x, xv.x, acc);
                acc = fmaf(wv.y, xv.y, acc);
                acc = fmaf(wv.z, xv.z, acc);
                acc = fmaf(wv.w, xv.w, acc);
            }
            float v = fmaxf(acc, 0.0f);
            h[((size_t)n << 6) + lane]  = f2bf(v);
            x0[((size_t)n << 6) + lane] = v;
        }
    }
}

// ---------------------------------------------------------------------------
// Gather core (bf16 h rows), batch-4: load FOUR adj entries first, then issue
// all four row loads -> ~8 loads in flight per wave (attacks the adj->row
// dependency serialization). lane = g*16 + c; group g walks e0+g step 4.
__device__ __forceinline__ float4 gather_node(const unsigned short* __restrict__ h_in,
                                              const int2* __restrict__ adj,
                                              int e0, int e1, int g, int c) {
    float4 acc = make_float4(0.f, 0.f, 0.f, 0.f);
    int e = e0 + g;
    for (; e + 16 <= e1; e += 16) {           // 4 edges for this group
        int2 a0 = adj[e];
        int2 a1 = adj[e + 4];
        int2 a2 = adj[e + 8];
        int2 a3 = adj[e + 12];
        ushort4 h0 = *reinterpret_cast<const ushort4*>(h_in + ((a0.x << 6) + (c << 2)));
        ushort4 h1 = *reinterpret_cast<const ushort4*>(h_in + ((a1.x << 6) + (c << 2)));
        ushort4 h2 = *reinterpret_cast<const ushort4*>(h_in + ((a2.x << 6) + (c << 2)));
        ushort4 h3 = *reinterpret_cast<const ushort4*>(h_in + ((a3.x << 6) + (c << 2)));
        float n0 = __int_as_float(a0.y), n1 = __int_as_float(a1.y);
        float n2 = __int_as_float(a2.y), n3 = __int_as_float(a3.y);
        acc.x = fmaf(n0, bf2f(h0.x), acc.x); acc.y = fmaf(n0, bf2f(h0.y), acc.y);
        acc.z = fmaf(n0, bf2f(h0.z), acc.z); acc.w = fmaf(n0, bf2f(h0.w), acc.w);
        acc.x = fmaf(n1, bf2f(h1.x), acc.x); acc.y = fmaf(n1, bf2f(h1.y), acc.y);
        acc.z = fmaf(n1, bf2f(h1.z), acc.z); acc.w = fmaf(n1, bf2f(h1.w), acc.w);
        acc.x = fmaf(n2, bf2f(h2.x), acc.x); acc.y = fmaf(n2, bf2f(h2.y), acc.y);
        acc.z = fmaf(n2, bf2f(h2.z), acc.z); acc.w = fmaf(n2, bf2f(h2.w), acc.w);
        acc.x = fmaf(n3, bf2f(h3.x), acc.x); acc.y = fmaf(n3, bf2f(h3.y), acc.y);
        acc.z = fmaf(n3, bf2f(h3.z), acc.z); acc.w = fmaf(n3, bf2f(h3.w), acc.w);
    }
    for (; e < e1; e += 4) {
        int2 a = adj[e];
        ushort4 hv = *reinterpret_cast<const ushort4*>(h_in + ((a.x << 6) + (c << 2)));
        float nrm = __int_as_float(a.y);
        acc.x = fmaf(nrm, bf2f(hv.x), acc.x);
        acc.y = fmaf(nrm, bf2f(hv.y), acc.y);
        acc.z = fmaf(nrm, bf2f(hv.z), acc.z);
        acc.w = fmaf(nrm, bf2f(hv.w), acc.w);
    }
    // reduce across the 4 groups (lanes differing in bits 4..5)
    acc.x += __shfl_xor(acc.x, 16); acc.y += __shfl_xor(acc.y, 16);
    acc.z += __shfl_xor(acc.z, 16); acc.w += __shfl_xor(acc.w, 16);
    acc.x += __shfl_xor(acc.x, 32); acc.y += __shfl_xor(acc.y, 32);
    acc.z += __shfl_xor(acc.z, 32); acc.w += __shfl_xor(acc.w, 32);
    return acc;
}

// Stage 5: GCNII layer (all 8). Slot-major W (16 slots x 64 rows float4).
__global__ __launch_bounds__(256, 8) void layer_mid(
        const unsigned short* __restrict__ h_in, unsigned short* __restrict__ h_out,
        const float* __restrict__ x0,
        const int* __restrict__ offsets, const int2* __restrict__ adj,
        const float* __restrict__ W, float beta) {
    __shared__ float4 WI4[16 * HIDC];   // 16KB
    __shared__ float  vecs[4][HIDC];
    int tid = threadIdx.x;
    const float4* W4 = reinterpret_cast<const float4*>(W);   // W[j][k] -> W4[j*16+s]
    for (int m = 0; m < 4; ++m) {
        int idx = tid + m * 256;               // idx = s*64 + j
        int s = idx >> 6, j = idx & 63;
        WI4[idx] = W4[j * 16 + s];
    }
    __syncthreads();
    int w = tid >> 6, lane = tid & 63;
    int g = lane >> 4, c = lane & 15;
    float omb = 1.0f - beta;

    for (int n0 = blockIdx.x * 4; n0 < NN; n0 += gridDim.x * 4) {
        int n = n0 + w;
        if (n < NN) {                          // uniform per wave
            int e0 = offsets[n], e1 = offsets[n + 1];
            float4 acc = gather_node(h_in, adj, e0, e1, g, c);
            if (g == 0) {
                const float4 x0v = *reinterpret_cast<const float4*>(x0 + ((n << 6) + (c << 2)));
                float4 aggv;
                aggv.x = fmaf(0.9f, acc.x, 0.1f * x0v.x);
                aggv.y = fmaf(0.9f, acc.y, 0.1f * x0v.y);
                aggv.z = fmaf(0.9f, acc.z, 0.1f * x0v.z);
                aggv.w = fmaf(0.9f, acc.w, 0.1f * x0v.w);
                *reinterpret_cast<float4*>(&vecs[w][c << 2]) = aggv;
            }
            WAVE_LDS_FENCE();
            float vagg = vecs[w][lane];
            float dot = 0.0f;
            #pragma unroll
            for (int s = 0; s < 16; ++s) {
                float4 wv = WI4[(s << 6) + lane];
                float4 vv = *reinterpret_cast<const float4*>(&vecs[w][s << 2]);
                dot = fmaf(wv.x, vv.x, dot);
                dot = fmaf(wv.y, vv.y, dot);
                dot = fmaf(wv.z, vv.z, dot);
                dot = fmaf(wv.w, vv.w, dot);
            }
            float hn = fmaxf(fmaf(beta, dot, omb * vagg), 0.0f);
            h_out[(n << 6) + lane] = f2bf(hn);
        }
    }
}

// Stage 6: out = h @ w_out^T + b_out (h bf16; slot-major W).
__global__ __launch_bounds__(256, 8) void out_gemm(const unsigned short* __restrict__ h,
                                                   const float* __restrict__ w_out,
                                                   const float* __restrict__ b_out,
                                                   float* __restrict__ out) {
    __shared__ float4 WI4[16 * HIDC];
    __shared__ float  vecs[4][HIDC];
    int tid = threadIdx.x;
    const float4* W4 = reinterpret_cast<const float4*>(w_out);
    for (int m = 0; m < 4; ++m) {
        int idx = tid + m * 256;
        int s = idx >> 6, j = idx & 63;
        WI4[idx] = W4[j * 16 + s];
    }
    __syncthreads();
    int w = tid >> 6, lane = tid & 63;
    float bj = b_out[lane];
    for (int n0 = blockIdx.x * 4; n0 < NN; n0 += gridDim.x * 4) {
        int n = n0 + w;
        if (n < NN) {
            vecs[w][lane] = bf2f(h[(n << 6) + lane]);
            WAVE_LDS_FENCE();
            float acc = bj;
            #pragma unroll
            for (int s = 0; s < 16; ++s) {
                float4 wv = WI4[(s << 6) + lane];
                float4 vv = *reinterpret_cast<const float4*>(&vecs[w][s << 2]);
                acc = fmaf(wv.x, vv.x, acc);
                acc = fmaf(wv.y, vv.y, acc);
                acc = fmaf(wv.z, vv.z, acc);
                acc = fmaf(wv.w, vv.w, acc);
            }
            out[(n << 6) + lane] = acc;
        }
    }
}

extern "C" void kernel_launch(void* const* d_in, const int* in_sizes, int n_in,
                              void* d_out, int out_size, void* d_ws, size_t ws_size,
                              hipStream_t stream) {
    const float* x      = (const float*)d_in[0];
    const void*  ei     = d_in[1];
    const float* w_in   = (const float*)d_in[2];
    const float* b_in   = (const float*)d_in[3];
    const float* conv_w = (const float*)d_in[4];
    const float* w_out  = (const float*)d_in[5];
    const float* b_out  = (const float*)d_in[6];
    float* out = (float*)d_out;

    char* ws = (char*)d_ws;
    size_t off = 0;
    auto alloc = [&](size_t bytes) -> void* {
        void* p = ws + off;
        off += (bytes + 255) & ~(size_t)255;
        return p;
    };
    int*   flag    = (int*)alloc(4);
    int*   degi    = (int*)alloc((size_t)NN * 4);
    float* dinv    = (float*)alloc((size_t)NN * 4);
    int*   offsets = (int*)alloc((size_t)(NN + 1) * 4);
    int*   cursor  = (int*)alloc((size_t)NN * 4);
    int*   bsum    = (int*)alloc((size_t)SCAN_B * 4);
    int2*  adj     = (int2*)alloc((size_t)TOT * 8);
    unsigned short* hA = (unsigned short*)alloc((size_t)NN * HIDC * 2);
    unsigned short* hB = (unsigned short*)alloc((size_t)NN * HIDC * 2);
    float* x0      = (float*)alloc((size_t)NN * HIDC * 4);

    hipMemsetAsync(flag, 0, 4, stream);
    hipMemsetAsync(degi, 0, (size_t)NN * 4, stream);
    detect_kernel<<<256, 256, 0, stream>>>((const long long*)ei, flag);
    deg_kernel<<<(TOT + 255) / 256, 256, 0, stream>>>(ei, flag, degi);
    dinv_kernel<<<(NN + 255) / 256, 256, 0, stream>>>(degi, dinv);
    scan_part<<<SCAN_B, 256, 0, stream>>>(degi, bsum);
    scan_bsum<<<1, 256, 0, stream>>>(bsum);
    scan_final<<<SCAN_B, 256, 0, stream>>>(degi, bsum, offsets);
    hipMemcpyAsync(cursor, offsets, (size_t)NN * 4, hipMemcpyDeviceToDevice, stream);
    fill_kernel<<<(TOT + 255) / 256, 256, 0, stream>>>(ei, flag, dinv, cursor, adj);
    in_gemm<<<1024, 512, 0, stream>>>(x, w_in, b_in, hA, x0);

    unsigned short* cur = hA;
    unsigned short* nxt = hB;
    for (int l = 0; l < LLAYERS; ++l) {
        float beta = logf(0.5f / (float)(l + 1) + 1.0f);
        const float* Wl = conv_w + (size_t)l * HIDC * HIDC;
        layer_mid<<<2048, 256, 0, stream>>>(cur, nxt, x0, offsets, adj, Wl, beta);
        unsigned short* t = cur; cur = nxt; nxt = t;
    }
    out_gemm<<<1024, 256, 0, stream>>>(cur, w_out, b_out, out);
}

// Round 15
// 430.495 us; speedup vs baseline: 1.0212x; 1.0212x over previous
//
#include <hip/hip_runtime.h>
#include <math.h>

#define NN 50000
#define EE 800000
#define INC 128
#define HIDC 64
#define OUTC 64
#define LLAYERS 8
#define TOT (EE + NN)
#define SCAN_B 200        // ceil(NN/256)
#define NB 196            // col buckets of 256 cols each
#define ABLK 512          // phase-A blocks
#define CHUNKA ((TOT + ABLK - 1) / ABLK)

// Wave-internal LDS fence (vecs[w]/xs[w] wave-private; no block barrier).
#define WAVE_LDS_FENCE() asm volatile("s_waitcnt lgkmcnt(0)" ::: "memory")

// bf16 <-> f32 (RTN-even pack; values are finite)
__device__ __forceinline__ float bf2f(unsigned short u) {
    return __uint_as_float(((unsigned int)u) << 16);
}
__device__ __forceinline__ unsigned short f2bf(float f) {
    unsigned int u = __float_as_uint(f);
    u += 0x7FFFu + ((u >> 16) & 1u);
    return (unsigned short)(u >> 16);
}

// ---------------------------------------------------------------------------
// Stage 0: int64-vs-int32 detect, SAMPLED: first 256 int64 views. If data is
// int32, each odd 32b word is a random index in [0,50000): P(all 128 zero)
// ~ (2e-5)^128 = 0. Deterministic given inputs.
__global__ void detect_kernel(const long long* __restrict__ p, int* __restrict__ flag) {
    long long v = p[threadIdx.x];
    if (v < 0 || v >= NN) atomicOr(flag, 1);   // flag=1 -> int32 layout
}

__device__ __forceinline__ int load_row(const void* ei, int is64, int e) {
    return is64 ? (int)((const long long*)ei)[e] : ((const int*)ei)[e];
}
__device__ __forceinline__ int load_col(const void* ei, int is64, int e) {
    return is64 ? (int)((const long long*)ei)[EE + e] : ((const int*)ei)[EE + e];
}

// ---------------------------------------------------------------------------
// CSR build, phase A0: per-bucket edge counts (LDS hist -> 196 global adds).
__global__ __launch_bounds__(256) void histA(const void* __restrict__ ei,
                                             const int* __restrict__ flag,
                                             int* __restrict__ bcnt) {
    __shared__ int h[NB];
    int tid = threadIdx.x;
    for (int i = tid; i < NB; i += 256) h[i] = 0;
    __syncthreads();
    int is64 = (*flag == 0);
    int lo = blockIdx.x * CHUNKA, hi = lo + CHUNKA; if (hi > TOT) hi = TOT;
    for (int e = lo + tid; e < hi; e += 256) {
        int c = (e < EE) ? load_col(ei, is64, e) : (e - EE);
        atomicAdd(&h[c >> 8], 1);
    }
    __syncthreads();
    for (int i = tid; i < NB; i += 256) if (h[i]) atomicAdd(&bcnt[i], h[i]);
}

// phase A1: exclusive scan of bucket counts -> bstart[NB+1], bcur init.
__global__ __launch_bounds__(256) void scan_buckets(const int* __restrict__ bcnt,
                                                    int* __restrict__ bstart,
                                                    int* __restrict__ bcur) {
    __shared__ int s[256];
    int t = threadIdx.x;
    int v = (t < NB) ? bcnt[t] : 0;
    s[t] = v;
    __syncthreads();
    for (int off = 1; off < 256; off <<= 1) {
        int a = (t >= off) ? s[t - off] : 0;
        __syncthreads();
        s[t] += a;
        __syncthreads();
    }
    if (t < NB) { int st = s[t] - v; bstart[t] = st; bcur[t] = st; }
    if (t == NB - 1) bstart[NB] = s[t];
}

// phase A2: scatter (src,col) into bucket-major barr. Each block reserves one
// contiguous run per bucket (LDS hist + one global atomic) -> line-dense
// writes. Degree counting fused (replaces the old deg_kernel pass).
__global__ __launch_bounds__(256) void bucket_scatter(const void* __restrict__ ei,
                                                      const int* __restrict__ flag,
                                                      int* __restrict__ bcur,
                                                      int2* __restrict__ barr,
                                                      int* __restrict__ degi) {
    __shared__ int h[NB];
    __shared__ int base[NB];
    int tid = threadIdx.x;
    for (int i = tid; i < NB; i += 256) h[i] = 0;
    __syncthreads();
    int is64 = (*flag == 0);
    int lo = blockIdx.x * CHUNKA, hi = lo + CHUNKA; if (hi > TOT) hi = TOT;
    for (int e = lo + tid; e < hi; e += 256) {
        int c = (e < EE) ? load_col(ei, is64, e) : (e - EE);
        atomicAdd(&h[c >> 8], 1);
    }
    __syncthreads();
    for (int i = tid; i < NB; i += 256) {
        int cnt = h[i];
        base[i] = cnt ? atomicAdd(&bcur[i], cnt) : 0;
        h[i] = 0;                                   // reuse as local cursor
    }
    __syncthreads();
    for (int e = lo + tid; e < hi; e += 256) {
        int r, c;
        if (e < EE) { r = load_row(ei, is64, e); c = load_col(ei, is64, e); }
        else        { r = e - EE; c = r; }
        int b = c >> 8;
        int p = base[b] + atomicAdd(&h[b], 1);
        barr[p] = make_int2(r, c);
        atomicAdd(&degi[c], 1);
    }
}

__global__ void dinv_kernel(const int* __restrict__ degi, float* __restrict__ dinv) {
    int i = blockIdx.x * blockDim.x + threadIdx.x;
    if (i < NN) {
        int d = degi[i];
        dinv[i] = d > 0 ? 1.0f / sqrtf((float)d) : 0.0f;
    }
}

// ---------------------------------------------------------------------------
// Stage 2: 3-kernel device-wide exclusive scan over degi -> offsets
__global__ __launch_bounds__(256) void scan_part(const int* __restrict__ degi,
                                                 int* __restrict__ bsum) {
    __shared__ int s[256];
    int t = threadIdx.x;
    int i = blockIdx.x * 256 + t;
    s[t] = (i < NN) ? degi[i] : 0;
    __syncthreads();
    for (int off = 128; off > 0; off >>= 1) {
        if (t < off) s[t] += s[t + off];
        __syncthreads();
    }
    if (t == 0) bsum[blockIdx.x] = s[0];
}

__global__ __launch_bounds__(256) void scan_bsum(int* __restrict__ bsum) {
    __shared__ int s[256];
    int t = threadIdx.x;
    int v = (t < SCAN_B) ? bsum[t] : 0;
    s[t] = v;
    __syncthreads();
    for (int off = 1; off < 256; off <<= 1) {
        int add = (t >= off) ? s[t - off] : 0;
        __syncthreads();
        s[t] += add;
        __syncthreads();
    }
    if (t < SCAN_B) bsum[t] = s[t] - v;   // exclusive
}

__global__ __launch_bounds__(256) void scan_final(const int* __restrict__ degi,
                                                  const int* __restrict__ bsum,
                                                  int* __restrict__ offsets) {
    __shared__ int s[256];
    int t = threadIdx.x;
    int i = blockIdx.x * 256 + t;
    int v = (i < NN) ? degi[i] : 0;
    s[t] = v;
    __syncthreads();
    for (int off = 1; off < 256; off <<= 1) {
        int add = (t >= off) ? s[t - off] : 0;
        __syncthreads();
        s[t] += add;
        __syncthreads();
    }
    if (i < NN) {
        int off_i = bsum[blockIdx.x] + s[t] - v;
        offsets[i] = off_i;
        if (i == NN - 1) offsets[NN] = off_i + v;
    }
}

// phase B: one block per bucket streams its barr region; adj writes confined
// to a block-exclusive ~35KB window -> lines merge in one L2 -> dense.
__global__ __launch_bounds__(256) void bucket_fill(const int2* __restrict__ barr,
                                                   const int* __restrict__ bstart,
                                                   const float* __restrict__ dinv,
                                                   int* __restrict__ cursor,
                                                   int2* __restrict__ adj) {
    int b = blockIdx.x;
    int lo = bstart[b], hi = bstart[b + 1];
    for (int i = lo + threadIdx.x; i < hi; i += 256) {
        int2 rc = barr[i];
        int pos = atomicAdd(&cursor[rc.y], 1);
        adj[pos] = make_int2(rc.x, __float_as_int(dinv[rc.x] * dinv[rc.y]));
    }
}

// ---------------------------------------------------------------------------
// Stage 4: h(bf16) = relu(x @ w_in^T + b_in); x0(fp32) = same. Slot-major W.
__global__ __launch_bounds__(512) void in_gemm(const float* __restrict__ x,
                                               const float* __restrict__ w_in,
                                               const float* __restrict__ b_in,
                                               unsigned short* __restrict__ h,
                                               float* __restrict__ x0) {
    __shared__ float4 WI4[32 * HIDC];   // [slot][row], 32KB
    __shared__ float  xs[8][INC];
    int tid = threadIdx.x;
    const float4* wf4 = reinterpret_cast<const float4*>(w_in);
    for (int m = 0; m < 4; ++m) {
        int idx = tid + m * 512;               // idx = s*64 + j
        int s = idx >> 6, j = idx & 63;
        WI4[idx] = wf4[j * 32 + s];
    }
    __syncthreads();
    int w = tid >> 6, lane = tid & 63;
    float bj = b_in[lane];
    for (int n0 = blockIdx.x * 8; n0 < NN; n0 += gridDim.x * 8) {
        int n = n0 + w;
        if (n < NN) {
            xs[w][lane]      = x[(size_t)n * INC + lane];
            xs[w][lane + 64] = x[(size_t)n * INC + 64 + lane];
            WAVE_LDS_FENCE();
            float acc = bj;
            #pragma unroll
            for (int s = 0; s < 32; ++s) {
                float4 wv = WI4[(s << 6) + lane];
                float4 xv = *reinterpret_cast<const float4*>(&xs[w][s << 2]);
                acc = fmaf(wv.x, xv.x, acc);
                acc = fmaf(wv.y, xv.y, acc);
                acc = fmaf(wv.z, xv.z, acc);
                acc = fmaf(wv.w, xv.w, acc);
            }
            float v = fmaxf(acc, 0.0f);
            h[((size_t)n << 6) + lane]  = f2bf(v);
            x0[((size_t)n << 6) + lane] = v;
        }
    }
}

// ---------------------------------------------------------------------------
// Gather core (bf16 rows, batch-4 for load overlap).
__device__ __forceinline__ float4 gather_node(const unsigned short* __restrict__ h_in,
                                              const int2* __restrict__ adj,
                                              int e0, int e1, int g, int c) {
    float4 acc = make_float4(0.f, 0.f, 0.f, 0.f);
    int e = e0 + g;
    for (; e + 16 <= e1; e += 16) {
        int2 a0 = adj[e];
        int2 a1 = adj[e + 4];
        int2 a2 = adj[e + 8];
        int2 a3 = adj[e + 12];
        ushort4 h0 = *reinterpret_cast<const ushort4*>(h_in + ((a0.x << 6) + (c << 2)));
        ushort4 h1 = *reinterpret_cast<const ushort4*>(h_in + ((a1.x << 6) + (c << 2)));
        ushort4 h2 = *reinterpret_cast<const ushort4*>(h_in + ((a2.x << 6) + (c << 2)));
        ushort4 h3 = *reinterpret_cast<const ushort4*>(h_in + ((a3.x << 6) + (c << 2)));
        float n0 = __int_as_float(a0.y), n1 = __int_as_float(a1.y);
        float n2 = __int_as_float(a2.y), n3 = __int_as_float(a3.y);
        acc.x = fmaf(n0, bf2f(h0.x), acc.x); acc.y = fmaf(n0, bf2f(h0.y), acc.y);
        acc.z = fmaf(n0, bf2f(h0.z), acc.z); acc.w = fmaf(n0, bf2f(h0.w), acc.w);
        acc.x = fmaf(n1, bf2f(h1.x), acc.x); acc.y = fmaf(n1, bf2f(h1.y), acc.y);
        acc.z = fmaf(n1, bf2f(h1.z), acc.z); acc.w = fmaf(n1, bf2f(h1.w), acc.w);
        acc.x = fmaf(n2, bf2f(h2.x), acc.x); acc.y = fmaf(n2, bf2f(h2.y), acc.y);
        acc.z = fmaf(n2, bf2f(h2.z), acc.z); acc.w = fmaf(n2, bf2f(h2.w), acc.w);
        acc.x = fmaf(n3, bf2f(h3.x), acc.x); acc.y = fmaf(n3, bf2f(h3.y), acc.y);
        acc.z = fmaf(n3, bf2f(h3.z), acc.z); acc.w = fmaf(n3, bf2f(h3.w), acc.w);
    }
    for (; e < e1; e += 4) {
        int2 a = adj[e];
        ushort4 hv = *reinterpret_cast<const ushort4*>(h_in + ((a.x << 6) + (c << 2)));
        float nrm = __int_as_float(a.y);
        acc.x = fmaf(nrm, bf2f(hv.x), acc.x);
        acc.y = fmaf(nrm, bf2f(hv.y), acc.y);
        acc.z = fmaf(nrm, bf2f(hv.z), acc.z);
        acc.w = fmaf(nrm, bf2f(hv.w), acc.w);
    }
    acc.x += __shfl_xor(acc.x, 16); acc.y += __shfl_xor(acc.y, 16);
    acc.z += __shfl_xor(acc.z, 16); acc.w += __shfl_xor(acc.w, 16);
    acc.x += __shfl_xor(acc.x, 32); acc.y += __shfl_xor(acc.y, 32);
    acc.z += __shfl_xor(acc.z, 32); acc.w += __shfl_xor(acc.w, 32);
    return acc;
}

// Stage 5: GCNII layer (all 8). Slot-major W, conflict-free b128 dot.
__global__ __launch_bounds__(256, 8) void layer_mid(
        const unsigned short* __restrict__ h_in, unsigned short* __restrict__ h_out,
        const float* __restrict__ x0,
        const int* __restrict__ offsets, const int2* __restrict__ adj,
        const float* __restrict__ W, float beta) {
    __shared__ float4 WI4[16 * HIDC];   // 16KB
    __shared__ float  vecs[4][HIDC];
    int tid = threadIdx.x;
    const float4* W4 = reinterpret_cast<const float4*>(W);
    for (int m = 0; m < 4; ++m) {
        int idx = tid + m * 256;
        int s = idx >> 6, j = idx & 63;
        WI4[idx] = W4[j * 16 + s];
    }
    __syncthreads();
    int w = tid >> 6, lane = tid & 63;
    int g = lane >> 4, c = lane & 15;
    float omb = 1.0f - beta;

    for (int n0 = blockIdx.x * 4; n0 < NN; n0 += gridDim.x * 4) {
        int n = n0 + w;
        if (n < NN) {
            int e0 = offsets[n], e1 = offsets[n + 1];
            float4 acc = gather_node(h_in, adj, e0, e1, g, c);
            if (g == 0) {
                const float4 x0v = *reinterpret_cast<const float4*>(x0 + ((n << 6) + (c << 2)));
                float4 aggv;
                aggv.x = fmaf(0.9f, acc.x, 0.1f * x0v.x);
                aggv.y = fmaf(0.9f, acc.y, 0.1f * x0v.y);
                aggv.z = fmaf(0.9f, acc.z, 0.1f * x0v.z);
                aggv.w = fmaf(0.9f, acc.w, 0.1f * x0v.w);
                *reinterpret_cast<float4*>(&vecs[w][c << 2]) = aggv;
            }
            WAVE_LDS_FENCE();
            float vagg = vecs[w][lane];
            float dot = 0.0f;
            #pragma unroll
            for (int s = 0; s < 16; ++s) {
                float4 wv = WI4[(s << 6) + lane];
                float4 vv = *reinterpret_cast<const float4*>(&vecs[w][s << 2]);
                dot = fmaf(wv.x, vv.x, dot);
                dot = fmaf(wv.y, vv.y, dot);
                dot = fmaf(wv.z, vv.z, dot);
                dot = fmaf(wv.w, vv.w, dot);
            }
            float hn = fmaxf(fmaf(beta, dot, omb * vagg), 0.0f);
            h_out[(n << 6) + lane] = f2bf(hn);
        }
    }
}

// Stage 6: out = h @ w_out^T + b_out.
__global__ __launch_bounds__(256, 8) void out_gemm(const unsigned short* __restrict__ h,
                                                   const float* __restrict__ w_out,
                                                   const float* __restrict__ b_out,
                                                   float* __restrict__ out) {
    __shared__ float4 WI4[16 * HIDC];
    __shared__ float  vecs[4][HIDC];
    int tid = threadIdx.x;
    const float4* W4 = reinterpret_cast<const float4*>(w_out);
    for (int m = 0; m < 4; ++m) {
        int idx = tid + m * 256;
        int s = idx >> 6, j = idx & 63;
        WI4[idx] = W4[j * 16 + s];
    }
    __syncthreads();
    int w = tid >> 6, lane = tid & 63;
    float bj = b_out[lane];
    for (int n0 = blockIdx.x * 4; n0 < NN; n0 += gridDim.x * 4) {
        int n = n0 + w;
        if (n < NN) {
            vecs[w][lane] = bf2f(h[(n << 6) + lane]);
            WAVE_LDS_FENCE();
            float acc = bj;
            #pragma unroll
            for (int s = 0; s < 16; ++s) {
                float4 wv = WI4[(s << 6) + lane];
                float4 vv = *reinterpret_cast<const float4*>(&vecs[w][s << 2]);
                acc = fmaf(wv.x, vv.x, acc);
                acc = fmaf(wv.y, vv.y, acc);
                acc = fmaf(wv.z, vv.z, acc);
                acc = fmaf(wv.w, vv.w, acc);
            }
            out[(n << 6) + lane] = acc;
        }
    }
}

extern "C" void kernel_launch(void* const* d_in, const int* in_sizes, int n_in,
                              void* d_out, int out_size, void* d_ws, size_t ws_size,
                              hipStream_t stream) {
    const float* x      = (const float*)d_in[0];
    const void*  ei     = d_in[1];
    const float* w_in   = (const float*)d_in[2];
    const float* b_in   = (const float*)d_in[3];
    const float* conv_w = (const float*)d_in[4];
    const float* w_out  = (const float*)d_in[5];
    const float* b_out  = (const float*)d_in[6];
    float* out = (float*)d_out;

    char* ws = (char*)d_ws;
    size_t off = 0;
    auto alloc = [&](size_t bytes) -> void* {
        void* p = ws + off;
        off += (bytes + 255) & ~(size_t)255;
        return p;
    };
    int*   flag    = (int*)alloc(4);
    int*   degi    = (int*)alloc((size_t)NN * 4);
    float* dinv    = (float*)alloc((size_t)NN * 4);
    int*   offsets = (int*)alloc((size_t)(NN + 1) * 4);
    int*   cursor  = (int*)alloc((size_t)NN * 4);
    int*   bsum    = (int*)alloc((size_t)SCAN_B * 4);
    int*   bcnt    = (int*)alloc((size_t)NB * 4);
    int*   bstart  = (int*)alloc((size_t)(NB + 1) * 4);
    int*   bcur    = (int*)alloc((size_t)NB * 4);
    int2*  adj     = (int2*)alloc((size_t)TOT * 8);
    unsigned short* hA = (unsigned short*)alloc((size_t)NN * HIDC * 2);
    unsigned short* hB = (unsigned short*)alloc((size_t)NN * HIDC * 2);
    float* x0      = (float*)alloc((size_t)NN * HIDC * 4);
    // barr (6.8 MB) aliases hA+hB (12.8 MB): dead before in_gemm writes hA.
    int2*  barr    = (int2*)hA;

    hipMemsetAsync(flag, 0, 4, stream);
    hipMemsetAsync(degi, 0, (size_t)NN * 4, stream);
    hipMemsetAsync(bcnt, 0, (size_t)NB * 4, stream);
    detect_kernel<<<1, 256, 0, stream>>>((const long long*)ei, flag);
    histA<<<ABLK, 256, 0, stream>>>(ei, flag, bcnt);
    scan_buckets<<<1, 256, 0, stream>>>(bcnt, bstart, bcur);
    bucket_scatter<<<ABLK, 256, 0, stream>>>(ei, flag, bcur, barr, degi);
    dinv_kernel<<<(NN + 255) / 256, 256, 0, stream>>>(degi, dinv);
    scan_part<<<SCAN_B, 256, 0, stream>>>(degi, bsum);
    scan_bsum<<<1, 256, 0, stream>>>(bsum);
    scan_final<<<SCAN_B, 256, 0, stream>>>(degi, bsum, offsets);
    hipMemcpyAsync(cursor, offsets, (size_t)NN * 4, hipMemcpyDeviceToDevice, stream);
    bucket_fill<<<NB, 256, 0, stream>>>(barr, bstart, dinv, cursor, adj);
    in_gemm<<<1024, 512, 0, stream>>>(x, w_in, b_in, hA, x0);

    unsigned short* cur = hA;
    unsigned short* nxt = hB;
    for (int l = 0; l < LLAYERS; ++l) {
        float beta = logf(0.5f / (float)(l + 1) + 1.0f);
        const float* Wl = conv_w + (size_t)l * HIDC * HIDC;
        layer_mid<<<2048, 256, 0, stream>>>(cur, nxt, x0, offsets, adj, Wl, beta);
        unsigned short* t = cur; cur = nxt; nxt = t;
    }
    out_gemm<<<1024, 256, 0, stream>>>(cur, w_out, b_out, out);
}

// Round 16
// 423.168 us; speedup vs baseline: 1.0389x; 1.0173x over previous
//
#include <hip/hip_runtime.h>
#include <math.h>

#define NN 50000
#define EE 800000
#define INC 128
#define HIDC 64
#define OUTC 64
#define LLAYERS 8
#define TOT (EE + NN)
#define SCAN_B 200        // ceil(NN/256)
#define NB 98             // col buckets of 512 cols each (98*512 = 50176 >= NN)
#define ABLK 64           // phase-A blocks -> runs of ~135 packed entries (~540B)
#define CHUNKA ((TOT + ABLK - 1) / ABLK)

// Wave-internal LDS fence (vecs[w]/xs[w] wave-private; no block barrier).
#define WAVE_LDS_FENCE() asm volatile("s_waitcnt lgkmcnt(0)" ::: "memory")

// bf16 <-> f32 (RTN-even pack; values are finite)
__device__ __forceinline__ float bf2f(unsigned short u) {
    return __uint_as_float(((unsigned int)u) << 16);
}
__device__ __forceinline__ unsigned short f2bf(float f) {
    unsigned int u = __float_as_uint(f);
    u += 0x7FFFu + ((u >> 16) & 1u);
    return (unsigned short)(u >> 16);
}

// ---------------------------------------------------------------------------
// Stage 0: int64-vs-int32 detect, sampled (first 256 int64 views; int32 data
// would need 128 consecutive zero odd-words to misdetect: P ~ (2e-5)^128 = 0).
__global__ void detect_kernel(const long long* __restrict__ p, int* __restrict__ flag) {
    long long v = p[threadIdx.x];
    if (v < 0 || v >= NN) atomicOr(flag, 1);   // flag=1 -> int32 layout
}

__device__ __forceinline__ int load_row(const void* ei, int is64, int e) {
    return is64 ? (int)((const long long*)ei)[e] : ((const int*)ei)[e];
}
__device__ __forceinline__ int load_col(const void* ei, int is64, int e) {
    return is64 ? (int)((const long long*)ei)[EE + e] : ((const int*)ei)[EE + e];
}

// ---------------------------------------------------------------------------
// CSR build, phase A0: per-bucket edge counts (LDS hist -> NB global adds).
__global__ __launch_bounds__(256) void histA(const void* __restrict__ ei,
                                             const int* __restrict__ flag,
                                             int* __restrict__ bcnt) {
    __shared__ int h[NB];
    int tid = threadIdx.x;
    for (int i = tid; i < NB; i += 256) h[i] = 0;
    __syncthreads();
    int is64 = (*flag == 0);
    int lo = blockIdx.x * CHUNKA, hi = lo + CHUNKA; if (hi > TOT) hi = TOT;
    for (int e = lo + tid; e < hi; e += 256) {
        int c = (e < EE) ? load_col(ei, is64, e) : (e - EE);
        atomicAdd(&h[c >> 9], 1);
    }
    __syncthreads();
    for (int i = tid; i < NB; i += 256) if (h[i]) atomicAdd(&bcnt[i], h[i]);
}

// phase A1: exclusive scan of bucket counts -> bstart[NB+1], bcur init.
__global__ __launch_bounds__(256) void scan_buckets(const int* __restrict__ bcnt,
                                                    int* __restrict__ bstart,
                                                    int* __restrict__ bcur) {
    __shared__ int s[256];
    int t = threadIdx.x;
    int v = (t < NB) ? bcnt[t] : 0;
    s[t] = v;
    __syncthreads();
    for (int off = 1; off < 256; off <<= 1) {
        int a = (t >= off) ? s[t - off] : 0;
        __syncthreads();
        s[t] += a;
        __syncthreads();
    }
    if (t < NB) { int st = s[t] - v; bstart[t] = st; bcur[t] = st; }
    if (t == NB - 1) bstart[NB] = s[t];
}

// phase A2: scatter PACKED (src<<9 | col&511) into bucket-major barr.
// 64 blocks x 98 buckets -> runs of ~135 x 4B = ~540B: line-dense writes.
__global__ __launch_bounds__(256) void bucket_scatter(const void* __restrict__ ei,
                                                      const int* __restrict__ flag,
                                                      int* __restrict__ bcur,
                                                      unsigned int* __restrict__ barr) {
    __shared__ int h[NB];
    __shared__ int base[NB];
    int tid = threadIdx.x;
    for (int i = tid; i < NB; i += 256) h[i] = 0;
    __syncthreads();
    int is64 = (*flag == 0);
    int lo = blockIdx.x * CHUNKA, hi = lo + CHUNKA; if (hi > TOT) hi = TOT;
    for (int e = lo + tid; e < hi; e += 256) {
        int c = (e < EE) ? load_col(ei, is64, e) : (e - EE);
        atomicAdd(&h[c >> 9], 1);
    }
    __syncthreads();
    for (int i = tid; i < NB; i += 256) {
        int cnt = h[i];
        base[i] = cnt ? atomicAdd(&bcur[i], cnt) : 0;
        h[i] = 0;                                   // reuse as local cursor
    }
    __syncthreads();
    for (int e = lo + tid; e < hi; e += 256) {
        int r, c;
        if (e < EE) { r = load_row(ei, is64, e); c = load_col(ei, is64, e); }
        else        { r = e - EE; c = r; }
        int b = c >> 9;
        int p = base[b] + atomicAdd(&h[b], 1);
        barr[p] = ((unsigned int)r << 9) | (unsigned int)(c & 511);
    }
}

// phase B0: per-col degree via per-bucket LDS counting (dense degi writes;
// replaces 850K global atomics AND the degi memset).
__global__ __launch_bounds__(256) void bucket_degcnt(const unsigned int* __restrict__ barr,
                                                     const int* __restrict__ bstart,
                                                     int* __restrict__ degi) {
    __shared__ int cnt[512];
    int b = blockIdx.x, t = threadIdx.x;
    for (int i = t; i < 512; i += 256) cnt[i] = 0;
    __syncthreads();
    int lo = bstart[b], hi = bstart[b + 1];
    for (int i = lo + t; i < hi; i += 256) atomicAdd(&cnt[barr[i] & 511u], 1);
    __syncthreads();
    int c0 = b << 9;
    for (int i = t; i < 512; i += 256) {
        int c = c0 + i;
        if (c < NN) degi[c] = cnt[i];
    }
}

__global__ void dinv_kernel(const int* __restrict__ degi, float* __restrict__ dinv) {
    int i = blockIdx.x * blockDim.x + threadIdx.x;
    if (i < NN) {
        int d = degi[i];
        dinv[i] = d > 0 ? 1.0f / sqrtf((float)d) : 0.0f;
    }
}

// ---------------------------------------------------------------------------
// Stage 2: 3-kernel device-wide exclusive scan over degi -> offsets
__global__ __launch_bounds__(256) void scan_part(const int* __restrict__ degi,
                                                 int* __restrict__ bsum) {
    __shared__ int s[256];
    int t = threadIdx.x;
    int i = blockIdx.x * 256 + t;
    s[t] = (i < NN) ? degi[i] : 0;
    __syncthreads();
    for (int off = 128; off > 0; off >>= 1) {
        if (t < off) s[t] += s[t + off];
        __syncthreads();
    }
    if (t == 0) bsum[blockIdx.x] = s[0];
}

__global__ __launch_bounds__(256) void scan_bsum(int* __restrict__ bsum) {
    __shared__ int s[256];
    int t = threadIdx.x;
    int v = (t < SCAN_B) ? bsum[t] : 0;
    s[t] = v;
    __syncthreads();
    for (int off = 1; off < 256; off <<= 1) {
        int add = (t >= off) ? s[t - off] : 0;
        __syncthreads();
        s[t] += add;
        __syncthreads();
    }
    if (t < SCAN_B) bsum[t] = s[t] - v;   // exclusive
}

__global__ __launch_bounds__(256) void scan_final(const int* __restrict__ degi,
                                                  const int* __restrict__ bsum,
                                                  int* __restrict__ offsets) {
    __shared__ int s[256];
    int t = threadIdx.x;
    int i = blockIdx.x * 256 + t;
    int v = (i < NN) ? degi[i] : 0;
    s[t] = v;
    __syncthreads();
    for (int off = 1; off < 256; off <<= 1) {
        int add = (t >= off) ? s[t - off] : 0;
        __syncthreads();
        s[t] += add;
        __syncthreads();
    }
    if (i < NN) {
        int off_i = bsum[blockIdx.x] + s[t] - v;
        offsets[i] = off_i;
        if (i == NN - 1) offsets[NN] = off_i + v;
    }
}

// phase B1: place into adj via LDS cursors (init from offsets). adj writes
// confined to a contiguous ~70KB per-bucket window -> L2-dense.
__global__ __launch_bounds__(256) void bucket_place(const unsigned int* __restrict__ barr,
                                                    const int* __restrict__ bstart,
                                                    const int* __restrict__ offsets,
                                                    const float* __restrict__ dinv,
                                                    int2* __restrict__ adj) {
    __shared__ int cur[512];
    int b = blockIdx.x, t = threadIdx.x;
    int c0 = b << 9;
    for (int i = t; i < 512; i += 256) {
        int c = c0 + i;
        cur[i] = (c < NN) ? offsets[c] : 0;
    }
    __syncthreads();
    int lo = bstart[b], hi = bstart[b + 1];
    for (int i = lo + t; i < hi; i += 256) {
        unsigned int v = barr[i];
        int r = (int)(v >> 9);
        int ci = (int)(v & 511u);
        int c = c0 + ci;
        int pos = atomicAdd(&cur[ci], 1);
        adj[pos] = make_int2(r, __float_as_int(dinv[r] * dinv[c]));
    }
}

// ---------------------------------------------------------------------------
// Stage 4: h(bf16) = relu(x @ w_in^T + b_in); x0(fp32) = same. Slot-major W.
__global__ __launch_bounds__(512) void in_gemm(const float* __restrict__ x,
                                               const float* __restrict__ w_in,
                                               const float* __restrict__ b_in,
                                               unsigned short* __restrict__ h,
                                               float* __restrict__ x0) {
    __shared__ float4 WI4[32 * HIDC];   // [slot][row], 32KB
    __shared__ float  xs[8][INC];
    int tid = threadIdx.x;
    const float4* wf4 = reinterpret_cast<const float4*>(w_in);
    for (int m = 0; m < 4; ++m) {
        int idx = tid + m * 512;               // idx = s*64 + j
        int s = idx >> 6, j = idx & 63;
        WI4[idx] = wf4[j * 32 + s];
    }
    __syncthreads();
    int w = tid >> 6, lane = tid & 63;
    float bj = b_in[lane];
    for (int n0 = blockIdx.x * 8; n0 < NN; n0 += gridDim.x * 8) {
        int n = n0 + w;
        if (n < NN) {
            xs[w][lane]      = x[(size_t)n * INC + lane];
            xs[w][lane + 64] = x[(size_t)n * INC + 64 + lane];
            WAVE_LDS_FENCE();
            float acc = bj;
            #pragma unroll
            for (int s = 0; s < 32; ++s) {
                float4 wv = WI4[(s << 6) + lane];
                float4 xv = *reinterpret_cast<const float4*>(&xs[w][s << 2]);
                acc = fmaf(wv.x, xv.x, acc);
                acc = fmaf(wv.y, xv.y, acc);
                acc = fmaf(wv.z, xv.z, acc);
                acc = fmaf(wv.w, xv.w, acc);
            }
            float v = fmaxf(acc, 0.0f);
            h[((size_t)n << 6) + lane]  = f2bf(v);
            x0[((size_t)n << 6) + lane] = v;
        }
    }
}

// ---------------------------------------------------------------------------
// Gather core (bf16 rows, batch-4 for load overlap).
__device__ __forceinline__ float4 gather_node(const unsigned short* __restrict__ h_in,
                                              const int2* __restrict__ adj,
                                              int e0, int e1, int g, int c) {
    float4 acc = make_float4(0.f, 0.f, 0.f, 0.f);
    int e = e0 + g;
    for (; e + 16 <= e1; e += 16) {
        int2 a0 = adj[e];
        int2 a1 = adj[e + 4];
        int2 a2 = adj[e + 8];
        int2 a3 = adj[e + 12];
        ushort4 h0 = *reinterpret_cast<const ushort4*>(h_in + ((a0.x << 6) + (c << 2)));
        ushort4 h1 = *reinterpret_cast<const ushort4*>(h_in + ((a1.x << 6) + (c << 2)));
        ushort4 h2 = *reinterpret_cast<const ushort4*>(h_in + ((a2.x << 6) + (c << 2)));
        ushort4 h3 = *reinterpret_cast<const ushort4*>(h_in + ((a3.x << 6) + (c << 2)));
        float n0 = __int_as_float(a0.y), n1 = __int_as_float(a1.y);
        float n2 = __int_as_float(a2.y), n3 = __int_as_float(a3.y);
        acc.x = fmaf(n0, bf2f(h0.x), acc.x); acc.y = fmaf(n0, bf2f(h0.y), acc.y);
        acc.z = fmaf(n0, bf2f(h0.z), acc.z); acc.w = fmaf(n0, bf2f(h0.w), acc.w);
        acc.x = fmaf(n1, bf2f(h1.x), acc.x); acc.y = fmaf(n1, bf2f(h1.y), acc.y);
        acc.z = fmaf(n1, bf2f(h1.z), acc.z); acc.w = fmaf(n1, bf2f(h1.w), acc.w);
        acc.x = fmaf(n2, bf2f(h2.x), acc.x); acc.y = fmaf(n2, bf2f(h2.y), acc.y);
        acc.z = fmaf(n2, bf2f(h2.z), acc.z); acc.w = fmaf(n2, bf2f(h2.w), acc.w);
        acc.x = fmaf(n3, bf2f(h3.x), acc.x); acc.y = fmaf(n3, bf2f(h3.y), acc.y);
        acc.z = fmaf(n3, bf2f(h3.z), acc.z); acc.w = fmaf(n3, bf2f(h3.w), acc.w);
    }
    for (; e < e1; e += 4) {
        int2 a = adj[e];
        ushort4 hv = *reinterpret_cast<const ushort4*>(h_in + ((a.x << 6) + (c << 2)));
        float nrm = __int_as_float(a.y);
        acc.x = fmaf(nrm, bf2f(hv.x), acc.x);
        acc.y = fmaf(nrm, bf2f(hv.y), acc.y);
        acc.z = fmaf(nrm, bf2f(hv.z), acc.z);
        acc.w = fmaf(nrm, bf2f(hv.w), acc.w);
    }
    acc.x += __shfl_xor(acc.x, 16); acc.y += __shfl_xor(acc.y, 16);
    acc.z += __shfl_xor(acc.z, 16); acc.w += __shfl_xor(acc.w, 16);
    acc.x += __shfl_xor(acc.x, 32); acc.y += __shfl_xor(acc.y, 32);
    acc.z += __shfl_xor(acc.z, 32); acc.w += __shfl_xor(acc.w, 32);
    return acc;
}

// Stage 5: GCNII layer (all 8). Slot-major W, conflict-free b128 dot.
__global__ __launch_bounds__(256, 8) void layer_mid(
        const unsigned short* __restrict__ h_in, unsigned short* __restrict__ h_out,
        const float* __restrict__ x0,
        const int* __restrict__ offsets, const int2* __restrict__ adj,
        const float* __restrict__ W, float beta) {
    __shared__ float4 WI4[16 * HIDC];   // 16KB
    __shared__ float  vecs[4][HIDC];
    int tid = threadIdx.x;
    const float4* W4 = reinterpret_cast<const float4*>(W);
    for (int m = 0; m < 4; ++m) {
        int idx = tid + m * 256;
        int s = idx >> 6, j = idx & 63;
        WI4[idx] = W4[j * 16 + s];
    }
    __syncthreads();
    int w = tid >> 6, lane = tid & 63;
    int g = lane >> 4, c = lane & 15;
    float omb = 1.0f - beta;

    for (int n0 = blockIdx.x * 4; n0 < NN; n0 += gridDim.x * 4) {
        int n = n0 + w;
        if (n < NN) {
            int e0 = offsets[n], e1 = offsets[n + 1];
            float4 acc = gather_node(h_in, adj, e0, e1, g, c);
            if (g == 0) {
                const float4 x0v = *reinterpret_cast<const float4*>(x0 + ((n << 6) + (c << 2)));
                float4 aggv;
                aggv.x = fmaf(0.9f, acc.x, 0.1f * x0v.x);
                aggv.y = fmaf(0.9f, acc.y, 0.1f * x0v.y);
                aggv.z = fmaf(0.9f, acc.z, 0.1f * x0v.z);
                aggv.w = fmaf(0.9f, acc.w, 0.1f * x0v.w);
                *reinterpret_cast<float4*>(&vecs[w][c << 2]) = aggv;
            }
            WAVE_LDS_FENCE();
            float vagg = vecs[w][lane];
            float dot = 0.0f;
            #pragma unroll
            for (int s = 0; s < 16; ++s) {
                float4 wv = WI4[(s << 6) + lane];
                float4 vv = *reinterpret_cast<const float4*>(&vecs[w][s << 2]);
                dot = fmaf(wv.x, vv.x, dot);
                dot = fmaf(wv.y, vv.y, dot);
                dot = fmaf(wv.z, vv.z, dot);
                dot = fmaf(wv.w, vv.w, dot);
            }
            float hn = fmaxf(fmaf(beta, dot, omb * vagg), 0.0f);
            h_out[(n << 6) + lane] = f2bf(hn);
        }
    }
}

// Stage 6: out = h @ w_out^T + b_out.
__global__ __launch_bounds__(256, 8) void out_gemm(const unsigned short* __restrict__ h,
                                                   const float* __restrict__ w_out,
                                                   const float* __restrict__ b_out,
                                                   float* __restrict__ out) {
    __shared__ float4 WI4[16 * HIDC];
    __shared__ float  vecs[4][HIDC];
    int tid = threadIdx.x;
    const float4* W4 = reinterpret_cast<const float4*>(w_out);
    for (int m = 0; m < 4; ++m) {
        int idx = tid + m * 256;
        int s = idx >> 6, j = idx & 63;
        WI4[idx] = W4[j * 16 + s];
    }
    __syncthreads();
    int w = tid >> 6, lane = tid & 63;
    float bj = b_out[lane];
    for (int n0 = blockIdx.x * 4; n0 < NN; n0 += gridDim.x * 4) {
        int n = n0 + w;
        if (n < NN) {
            vecs[w][lane] = bf2f(h[(n << 6) + lane]);
            WAVE_LDS_FENCE();
            float acc = bj;
            #pragma unroll
            for (int s = 0; s < 16; ++s) {
                float4 wv = WI4[(s << 6) + lane];
                float4 vv = *reinterpret_cast<const float4*>(&vecs[w][s << 2]);
                acc = fmaf(wv.x, vv.x, acc);
                acc = fmaf(wv.y, vv.y, acc);
                acc = fmaf(wv.z, vv.z, acc);
                acc = fmaf(wv.w, vv.w, acc);
            }
            out[(n << 6) + lane] = acc;
        }
    }
}

extern "C" void kernel_launch(void* const* d_in, const int* in_sizes, int n_in,
                              void* d_out, int out_size, void* d_ws, size_t ws_size,
                              hipStream_t stream) {
    const float* x      = (const float*)d_in[0];
    const void*  ei     = d_in[1];
    const float* w_in   = (const float*)d_in[2];
    const float* b_in   = (const float*)d_in[3];
    const float* conv_w = (const float*)d_in[4];
    const float* w_out  = (const float*)d_in[5];
    const float* b_out  = (const float*)d_in[6];
    float* out = (float*)d_out;

    char* ws = (char*)d_ws;
    size_t off = 0;
    auto alloc = [&](size_t bytes) -> void* {
        void* p = ws + off;
        off += (bytes + 255) & ~(size_t)255;
        return p;
    };
    int*   flag    = (int*)alloc(4);
    int*   degi    = (int*)alloc((size_t)NN * 4);
    float* dinv    = (float*)alloc((size_t)NN * 4);
    int*   offsets = (int*)alloc((size_t)(NN + 1) * 4);
    int*   bsum    = (int*)alloc((size_t)SCAN_B * 4);
    int*   bcnt    = (int*)alloc((size_t)NB * 4);
    int*   bstart  = (int*)alloc((size_t)(NB + 1) * 4);
    int*   bcur    = (int*)alloc((size_t)NB * 4);
    int2*  adj     = (int2*)alloc((size_t)TOT * 8);
    unsigned short* hA = (unsigned short*)alloc((size_t)NN * HIDC * 2);
    unsigned short* hB = (unsigned short*)alloc((size_t)NN * HIDC * 2);
    float* x0      = (float*)alloc((size_t)NN * HIDC * 4);
    // barr (3.4 MB packed) aliases hA (6.4 MB): consumed by bucket_place
    // before in_gemm writes hA.
    unsigned int* barr = (unsigned int*)hA;

    hipMemsetAsync(flag, 0, 4, stream);
    hipMemsetAsync(bcnt, 0, (size_t)NB * 4, stream);
    detect_kernel<<<1, 256, 0, stream>>>((const long long*)ei, flag);
    histA<<<ABLK, 256, 0, stream>>>(ei, flag, bcnt);
    scan_buckets<<<1, 256, 0, stream>>>(bcnt, bstart, bcur);
    bucket_scatter<<<ABLK, 256, 0, stream>>>(ei, flag, bcur, barr);
    bucket_degcnt<<<NB, 256, 0, stream>>>(barr, bstart, degi);
    dinv_kernel<<<(NN + 255) / 256, 256, 0, stream>>>(degi, dinv);
    scan_part<<<SCAN_B, 256, 0, stream>>>(degi, bsum);
    scan_bsum<<<1, 256, 0, stream>>>(bsum);
    scan_final<<<SCAN_B, 256, 0, stream>>>(degi, bsum, offsets);
    bucket_place<<<NB, 256, 0, stream>>>(barr, bstart, offsets, dinv, adj);
    in_gemm<<<1024, 512, 0, stream>>>(x, w_in, b_in, hA, x0);

    unsigned short* cur = hA;
    unsigned short* nxt = hB;
    for (int l = 0; l < LLAYERS; ++l) {
        float beta = logf(0.5f / (float)(l + 1) + 1.0f);
        const float* Wl = conv_w + (size_t)l * HIDC * HIDC;
        layer_mid<<<2048, 256, 0, stream>>>(cur, nxt, x0, offsets, adj, Wl, beta);
        unsigned short* t = cur; cur = nxt; nxt = t;
    }
    out_gemm<<<1024, 256, 0, stream>>>(cur, w_out, b_out, out);
}